// Round 5
// baseline (350.959 us; speedup 1.0000x reference)
//
#include <hip/hip_runtime.h>

typedef unsigned short u16;
typedef __attribute__((ext_vector_type(8))) short bf16x8;
typedef __attribute__((ext_vector_type(4))) float f32x4;

__device__ inline u16 f2b(float f) {
    unsigned u;
    __builtin_memcpy(&u, &f, 4);
    unsigned r = u + 0x7FFF + ((u >> 16) & 1);  // RNE
    return (u16)(r >> 16);
}

__device__ inline bf16x8 pack8(const float* p) {
    union { u16 us[8]; bf16x8 v; } r;
#pragma unroll
    for (int i = 0; i < 8; i++) r.us[i] = f2b(p[i]);
    return r.v;
}

// async global->LDS, 16B per lane. LDS dest must be wave-uniform base + lane*16.
__device__ inline void gload16(const void* g, void* l) {
    __builtin_amdgcn_global_load_lds((__attribute__((address_space(1))) void*)g,
                                     (__attribute__((address_space(3))) void*)l, 16, 0, 0);
}

// ---------------------------------------------------------------------------
// One-shot fp32 -> bf16: x (4096 blocks) then wq,wk,wv,wo (128 each) into wb.
// ---------------------------------------------------------------------------
__global__ __launch_bounds__(256) void conv_kernel(const float* __restrict__ x,
                                                   const float* __restrict__ wq,
                                                   const float* __restrict__ wk,
                                                   const float* __restrict__ wv,
                                                   const float* __restrict__ wo,
                                                   u16* __restrict__ xb, u16* __restrict__ wb) {
    const int bid = blockIdx.x;
    const float* src;
    u16* dst;
    size_t base;
    if (bid < 4096) {
        src = x; dst = xb; base = (size_t)bid * 2048;
    } else {
        const int wsel = (bid - 4096) >> 7;
        src = (wsel == 0) ? wq : (wsel == 1) ? wk : (wsel == 2) ? wv : wo;
        dst = wb + (size_t)wsel * 262144;
        base = (size_t)((bid - 4096) & 127) * 2048;
    }
    const size_t idx = base + (size_t)threadIdx.x * 8;
    float a[8];
    *(float4*)&a[0] = *(const float4*)&src[idx];
    *(float4*)&a[4] = *(const float4*)&src[idx + 4];
    *(bf16x8*)&dst[idx] = pack8(a);
}

// ---------------------------------------------------------------------------
// bf16 GEMM (m97-style): C[m][n] = sum_k A[m][k]*W[n][k] + bias[n].
// global_load_lds 16B staging, 128x128 tile, BK=32, 4 waves, 4x4 16x16x32 frags.
// MODE 0: N=1536 (q|k|v rows of wb); scatter Q*0.125,K -> (s,h,tok,hd),
//         V -> transposed (s,h,hd,tok). MODE 1: fp32 row-major out (d_out).
// ---------------------------------------------------------------------------
template <int MODE>
__global__ __launch_bounds__(256) void gemm_kernel(const u16* __restrict__ A,
                                                   const u16* __restrict__ W,
                                                   const float* __restrict__ B0,
                                                   const float* __restrict__ B1,
                                                   const float* __restrict__ B2,
                                                   void* __restrict__ O0v, u16* __restrict__ O1,
                                                   u16* __restrict__ O2) {
    const int m0 = blockIdx.x * 128;
    const int n0 = blockIdx.y * 128;
    const int seg = (MODE == 0) ? (n0 >> 9) : 0;
    const int nl0 = (MODE == 0) ? (n0 & 511) : n0;
    const float* Bb = (seg == 0) ? B0 : (seg == 1) ? B1 : B2;
    u16* O = (seg == 0) ? (u16*)O0v : (seg == 1) ? O1 : O2;

    __shared__ __align__(16) u16 Al[128 * 32];
    __shared__ __align__(16) u16 Bl[128 * 32];

    const int tid = threadIdx.x;
    const int lane = tid & 63, wave = tid >> 6;
    const int quad = lane >> 4, col = lane & 15;
    const int wm = wave >> 1, wn = wave & 1;

    f32x4 acc[4][4];
#pragma unroll
    for (int i = 0; i < 4; i++)
#pragma unroll
        for (int j = 0; j < 4; j++) acc[i][j] = (f32x4){0.f, 0.f, 0.f, 0.f};

    for (int k0 = 0; k0 < 512; k0 += 32) {
#pragma unroll
        for (int sh = 0; sh < 4; sh++) {
            const int c = tid + sh * 256;  // 0..511 -> A tile, 512..1023 -> W tile
            const int cl = c & 511;
            const int row = cl >> 2, cc = (cl & 3) * 8;
            if (c < 512)
                gload16(&A[(size_t)(m0 + row) * 512 + k0 + cc], &Al[cl * 8]);
            else
                gload16(&W[(size_t)(n0 + row) * 512 + k0 + cc], &Bl[cl * 8]);
        }
        __syncthreads();
        bf16x8 af[4], bfr[4];
#pragma unroll
        for (int t = 0; t < 4; t++) {
            af[t] = *(const bf16x8*)&Al[(wm * 64 + t * 16 + col) * 32 + quad * 8];
            bfr[t] = *(const bf16x8*)&Bl[(wn * 64 + t * 16 + col) * 32 + quad * 8];
        }
#pragma unroll
        for (int i = 0; i < 4; i++)
#pragma unroll
            for (int j = 0; j < 4; j++)
                acc[i][j] = __builtin_amdgcn_mfma_f32_16x16x32_bf16(af[i], bfr[j], acc[i][j], 0, 0, 0);
        __syncthreads();
    }

    float bias[4];
#pragma unroll
    for (int j = 0; j < 4; j++) bias[j] = Bb[nl0 + wn * 64 + j * 16 + col];

#pragma unroll
    for (int i = 0; i < 4; i++) {
        const int mbase = m0 + wm * 64 + i * 16 + quad * 4;
#pragma unroll
        for (int j = 0; j < 4; j++) {
            const int nl = nl0 + wn * 64 + j * 16 + col;
            if (MODE == 1) {
                float* Of = (float*)O0v;  // fp32 final output
#pragma unroll
                for (int r = 0; r < 4; r++)
                    Of[(size_t)(mbase + r) * 512 + nl] = acc[i][j][r] + bias[j];
            } else {
                const int h = nl >> 6, hd = nl & 63;
                if (seg < 2) {
                    const float qs = (seg == 0) ? 0.125f : 1.f;  // pre-scale Q by 1/sqrt(64)
#pragma unroll
                    for (int r = 0; r < 4; r++) {
                        int m = mbase + r;
                        int s = m >> 10, tok = m & 1023;
                        O[(size_t)((s * 8 + h) * 1024 + tok) * 64 + hd] =
                            f2b((acc[i][j][r] + bias[j]) * qs);
                    }
                } else {
                    // V transposed: ((s*8+h)*64 + hd)*1024 + tok
                    int s = mbase >> 10, tok0 = mbase & 1023;
                    union { u16 us[4]; uint2 v; } pk;
#pragma unroll
                    for (int r = 0; r < 4; r++) pk.us[r] = f2b(acc[i][j][r] + bias[j]);
                    *(uint2*)&O[(size_t)((s * 8 + h) * 64 + hd) * 1024 + tok0] = pk.v;
                }
            }
        }
    }
}

// ---------------------------------------------------------------------------
// Attention v3: 2 waves/block, key-split (wave w does kt = w, w+2, ...).
// Each wave: 64 q-rows x 512 keys; cross-wave combine via LDS at the end.
// den computed as P @ ones by MFMA (lands row-indexed in C-layout: no
// transpose, no shfl chain). XCD-aware decode: head = bid&127 -> all 16
// qt-blocks of a head are == mod 8 -> same XCD -> K/V L2 reuse.
// ---------------------------------------------------------------------------
__global__ __launch_bounds__(128, 3) void attn_kernel(const u16* __restrict__ Q,
                                                      const u16* __restrict__ Kp,
                                                      const u16* __restrict__ Vt,
                                                      u16* __restrict__ Ctx) {
    constexpr int SP = 72;  // P row stride: 16B-aligned frag reads, non-pow2 banks
    __shared__ union __align__(16) {
        u16 pl[2][64 * SP];                               // loop phase: per-wave P tiles
        struct { float cbuf[64 * 65]; float dbuf[64]; } c;  // combine phase (barrier-separated)
    } sm;

    const int bid = blockIdx.x;
    const int head = bid & 127;  // same-head blocks: bid == head (mod 128) -> same XCD (%8)
    const int qt = bid >> 7;
    const int s = head >> 3, h = head & 7;
    const u16* Qh = Q + (size_t)head * 65536;
    const u16* Kh = Kp + (size_t)head * 65536;
    const u16* Vh = Vt + (size_t)head * 65536;

    const int tid = threadIdx.x;
    const int lane = tid & 63, wave = tid >> 6;
    const int quad = lane >> 4, col = lane & 15;
    const int q0 = qt * 64;

    // ones B-fragment for den = P @ ones
    union { u16 us[8]; bf16x8 v; } one;
#pragma unroll
    for (int i = 0; i < 8; i++) one.us[i] = 0x3F80;
    const bf16x8 onesf = one.v;

    // Q fragments (B-operand: lane holds Q[q=col][hd=quad*8+j]), loaded once
    bf16x8 qf[4][2];
#pragma unroll
    for (int nt = 0; nt < 4; nt++)
#pragma unroll
        for (int kk = 0; kk < 2; kk++)
            qf[nt][kk] = *(const bf16x8*)&Qh[(size_t)(q0 + nt * 16 + col) * 64 + kk * 32 + quad * 8];

    f32x4 cacc[4][4];
#pragma unroll
    for (int i = 0; i < 4; i++)
#pragma unroll
        for (int j = 0; j < 4; j++) cacc[i][j] = (f32x4){0.f, 0.f, 0.f, 0.f};
    f32x4 dacc[4];
#pragma unroll
    for (int i = 0; i < 4; i++) dacc[i] = (f32x4){0.f, 0.f, 0.f, 0.f};

    for (int kt = wave; kt < 16; kt += 2) {
        const int k0 = kt * 64;

        // hoist V loads: QK MFMAs + pack cover their latency
        bf16x8 vf[2][4];
#pragma unroll
        for (int kk = 0; kk < 2; kk++)
#pragma unroll
            for (int nt = 0; nt < 4; nt++)
                vf[kk][nt] =
                    *(const bf16x8*)&Vh[(size_t)(nt * 16 + col) * 1024 + k0 + kk * 32 + quad * 8];

        bf16x8 kf[2][4];
#pragma unroll
        for (int kk = 0; kk < 2; kk++)
#pragma unroll
            for (int mt = 0; mt < 4; mt++)
                kf[kk][mt] =
                    *(const bf16x8*)&Kh[(size_t)(k0 + mt * 16 + col) * 64 + kk * 32 + quad * 8];

        f32x4 sacc[4][4];
#pragma unroll
        for (int i = 0; i < 4; i++)
#pragma unroll
            for (int j = 0; j < 4; j++) sacc[i][j] = (f32x4){0.f, 0.f, 0.f, 0.f};
#pragma unroll
        for (int kk = 0; kk < 2; kk++)
#pragma unroll
            for (int mt = 0; mt < 4; mt++)
#pragma unroll
                for (int nt = 0; nt < 4; nt++)
                    sacc[mt][nt] =
                        __builtin_amdgcn_mfma_f32_16x16x32_bf16(kf[kk][mt], qf[nt][kk], sacc[mt][nt], 0, 0, 0);

        // relu + cheap bf16 pack (round-half-up + v_perm); no VALU denominator
#pragma unroll
        for (int nt = 0; nt < 4; nt++) {
#pragma unroll
            for (int mt = 0; mt < 4; mt++) {
                unsigned u0 = __float_as_uint(fmaxf(sacc[mt][nt][0], 0.f)) + 0x8000u;
                unsigned u1 = __float_as_uint(fmaxf(sacc[mt][nt][1], 0.f)) + 0x8000u;
                unsigned u2 = __float_as_uint(fmaxf(sacc[mt][nt][2], 0.f)) + 0x8000u;
                unsigned u3 = __float_as_uint(fmaxf(sacc[mt][nt][3], 0.f)) + 0x8000u;
                uint2 pk;
                pk.x = __builtin_amdgcn_perm(u1, u0, 0x07060302);  // [u1.hi : u0.hi]
                pk.y = __builtin_amdgcn_perm(u3, u2, 0x07060302);
                // S^T C-layout: row(key)=mt*16+quad*4+r, col(q)=nt*16+col -> P[q][key]
                *(uint2*)&sm.pl[wave][(nt * 16 + col) * SP + mt * 16 + quad * 4] = pk;
            }
        }

        // P @ V  (+ den = P @ ones, row-indexed in C-layout)
#pragma unroll
        for (int kk = 0; kk < 2; kk++) {
            bf16x8 pf[4];
#pragma unroll
            for (int mt = 0; mt < 4; mt++)
                pf[mt] = *(const bf16x8*)&sm.pl[wave][(mt * 16 + col) * SP + kk * 32 + quad * 8];
#pragma unroll
            for (int mt = 0; mt < 4; mt++)
                dacc[mt] = __builtin_amdgcn_mfma_f32_16x16x32_bf16(pf[mt], onesf, dacc[mt], 0, 0, 0);
#pragma unroll
            for (int mt = 0; mt < 4; mt++)
#pragma unroll
                for (int nt = 0; nt < 4; nt++)
                    cacc[mt][nt] =
                        __builtin_amdgcn_mfma_f32_16x16x32_bf16(pf[mt], vf[kk][nt], cacc[mt][nt], 0, 0, 0);
        }
    }

    // ---- cross-wave combine (pl -> cbuf alias is barrier-separated) ----
    __syncthreads();
    if (wave == 1) {
#pragma unroll
        for (int mt = 0; mt < 4; mt++) {
#pragma unroll
            for (int nt = 0; nt < 4; nt++)
#pragma unroll
                for (int r = 0; r < 4; r++)
                    sm.c.cbuf[(mt * 16 + quad * 4 + r) * 65 + nt * 16 + col] = cacc[mt][nt][r];
            if (col == 0)
#pragma unroll
                for (int r = 0; r < 4; r++) sm.c.dbuf[mt * 16 + quad * 4 + r] = dacc[mt][r];
        }
    }
    __syncthreads();
    if (wave == 0) {
#pragma unroll
        for (int mt = 0; mt < 4; mt++) {
            float inv[4];
#pragma unroll
            for (int r = 0; r < 4; r++)
                inv[r] = 1.f / (dacc[mt][r] + sm.c.dbuf[mt * 16 + quad * 4 + r] + 1e-6f);
#pragma unroll
            for (int nt = 0; nt < 4; nt++) {
#pragma unroll
                for (int r = 0; r < 4; r++) {
                    const int row = mt * 16 + quad * 4 + r;
                    const float v = cacc[mt][nt][r] + sm.c.cbuf[row * 65 + nt * 16 + col];
                    const size_t grow = (size_t)(s * 1024 + q0 + row);
                    Ctx[grow * 512 + h * 64 + nt * 16 + col] = f2b(v * inv[r]);
                }
            }
        }
    }
}

extern "C" void kernel_launch(void* const* d_in, const int* in_sizes, int n_in, void* d_out,
                              int out_size, void* d_ws, size_t ws_size, hipStream_t stream) {
    const float* x = (const float*)d_in[0];
    const float* wq = (const float*)d_in[1];
    const float* bq = (const float*)d_in[2];
    const float* wk = (const float*)d_in[3];
    const float* bk = (const float*)d_in[4];
    const float* wv = (const float*)d_in[5];
    const float* bv = (const float*)d_in[6];
    const float* wo = (const float*)d_in[7];
    const float* bo = (const float*)d_in[8];

    const size_t E = 16384ull * 512ull;
    u16* xb = (u16*)d_ws;  // bf16 x; aliased as ctx after gemm0 consumes it
    u16* cw = xb;
    u16* wb = xb + E;      // bf16 wq|wk|wv|wo
    u16* qw = wb + 4 * 262144;
    u16* kw = qw + E;
    u16* vw = kw + E;

    conv_kernel<<<dim3(4096 + 512), 256, 0, stream>>>(x, wq, wk, wv, wo, xb, wb);
    gemm_kernel<0><<<dim3(128, 12), 256, 0, stream>>>(xb, wb, bq, bk, bv, qw, kw, vw);
    attn_kernel<<<dim3(2048), 128, 0, stream>>>(qw, kw, vw, cw);
    gemm_kernel<1><<<dim3(128, 4), 256, 0, stream>>>(cw, wb + 3 * 262144, bo, nullptr, nullptr,
                                                     d_out, nullptr, nullptr);
}

// Round 6
// 288.721 us; speedup vs baseline: 1.2156x; 1.2156x over previous
//
#include <hip/hip_runtime.h>

typedef unsigned short u16;
typedef __attribute__((ext_vector_type(8))) short bf16x8;
typedef __attribute__((ext_vector_type(4))) float f32x4;

__device__ inline u16 f2b(float f) {
    unsigned u;
    __builtin_memcpy(&u, &f, 4);
    unsigned r = u + 0x7FFF + ((u >> 16) & 1);  // RNE
    return (u16)(r >> 16);
}

__device__ inline bf16x8 pack8(const float* p) {
    union { u16 us[8]; bf16x8 v; } r;
#pragma unroll
    for (int i = 0; i < 8; i++) r.us[i] = f2b(p[i]);
    return r.v;
}

// async global->LDS, 16B per lane. LDS dest must be wave-uniform base + lane*16.
__device__ inline void gload16(const void* g, void* l) {
    __builtin_amdgcn_global_load_lds((__attribute__((address_space(1))) void*)g,
                                     (__attribute__((address_space(3))) void*)l, 16, 0, 0);
}

// ---------------------------------------------------------------------------
// One-shot fp32 -> bf16: x (4096 blocks) then wq,wk,wv,wo (128 each) into wb.
// ---------------------------------------------------------------------------
__global__ __launch_bounds__(256) void conv_kernel(const float* __restrict__ x,
                                                   const float* __restrict__ wq,
                                                   const float* __restrict__ wk,
                                                   const float* __restrict__ wv,
                                                   const float* __restrict__ wo,
                                                   u16* __restrict__ xb, u16* __restrict__ wb) {
    const int bid = blockIdx.x;
    const float* src;
    u16* dst;
    size_t base;
    if (bid < 4096) {
        src = x; dst = xb; base = (size_t)bid * 2048;
    } else {
        const int wsel = (bid - 4096) >> 7;
        src = (wsel == 0) ? wq : (wsel == 1) ? wk : (wsel == 2) ? wv : wo;
        dst = wb + (size_t)wsel * 262144;
        base = (size_t)((bid - 4096) & 127) * 2048;
    }
    const size_t idx = base + (size_t)threadIdx.x * 8;
    float a[8];
    *(float4*)&a[0] = *(const float4*)&src[idx];
    *(float4*)&a[4] = *(const float4*)&src[idx + 4];
    *(bf16x8*)&dst[idx] = pack8(a);
}

// ---------------------------------------------------------------------------
// bf16 GEMM (m97-style): C[m][n] = sum_k A[m][k]*W[n][k] + bias[n].
// global_load_lds 16B staging, 128x128 tile, BK=32, 4 waves, 4x4 16x16x32 frags.
// MODE 0: N=1536 (q|k|v rows of wb); scatter Q*0.125,K -> (s,h,tok,hd),
//         V -> transposed (s,h,hd,tok). MODE 1: fp32 row-major out (d_out).
// ---------------------------------------------------------------------------
template <int MODE>
__global__ __launch_bounds__(256) void gemm_kernel(const u16* __restrict__ A,
                                                   const u16* __restrict__ W,
                                                   const float* __restrict__ B0,
                                                   const float* __restrict__ B1,
                                                   const float* __restrict__ B2,
                                                   void* __restrict__ O0v, u16* __restrict__ O1,
                                                   u16* __restrict__ O2) {
    const int m0 = blockIdx.x * 128;
    const int n0 = blockIdx.y * 128;
    const int seg = (MODE == 0) ? (n0 >> 9) : 0;
    const int nl0 = (MODE == 0) ? (n0 & 511) : n0;
    const float* Bb = (seg == 0) ? B0 : (seg == 1) ? B1 : B2;
    u16* O = (seg == 0) ? (u16*)O0v : (seg == 1) ? O1 : O2;

    __shared__ __align__(16) u16 Al[128 * 32];
    __shared__ __align__(16) u16 Bl[128 * 32];

    const int tid = threadIdx.x;
    const int lane = tid & 63, wave = tid >> 6;
    const int quad = lane >> 4, col = lane & 15;
    const int wm = wave >> 1, wn = wave & 1;

    f32x4 acc[4][4];
#pragma unroll
    for (int i = 0; i < 4; i++)
#pragma unroll
        for (int j = 0; j < 4; j++) acc[i][j] = (f32x4){0.f, 0.f, 0.f, 0.f};

    for (int k0 = 0; k0 < 512; k0 += 32) {
#pragma unroll
        for (int sh = 0; sh < 4; sh++) {
            const int c = tid + sh * 256;  // 0..511 -> A tile, 512..1023 -> W tile
            const int cl = c & 511;
            const int row = cl >> 2, cc = (cl & 3) * 8;
            if (c < 512)
                gload16(&A[(size_t)(m0 + row) * 512 + k0 + cc], &Al[cl * 8]);
            else
                gload16(&W[(size_t)(n0 + row) * 512 + k0 + cc], &Bl[cl * 8]);
        }
        __syncthreads();
        bf16x8 af[4], bfr[4];
#pragma unroll
        for (int t = 0; t < 4; t++) {
            af[t] = *(const bf16x8*)&Al[(wm * 64 + t * 16 + col) * 32 + quad * 8];
            bfr[t] = *(const bf16x8*)&Bl[(wn * 64 + t * 16 + col) * 32 + quad * 8];
        }
#pragma unroll
        for (int i = 0; i < 4; i++)
#pragma unroll
            for (int j = 0; j < 4; j++)
                acc[i][j] = __builtin_amdgcn_mfma_f32_16x16x32_bf16(af[i], bfr[j], acc[i][j], 0, 0, 0);
        __syncthreads();
    }

    float bias[4];
#pragma unroll
    for (int j = 0; j < 4; j++) bias[j] = Bb[nl0 + wn * 64 + j * 16 + col];

#pragma unroll
    for (int i = 0; i < 4; i++) {
        const int mbase = m0 + wm * 64 + i * 16 + quad * 4;
#pragma unroll
        for (int j = 0; j < 4; j++) {
            const int nl = nl0 + wn * 64 + j * 16 + col;
            if (MODE == 1) {
                float* Of = (float*)O0v;  // fp32 final output
#pragma unroll
                for (int r = 0; r < 4; r++)
                    Of[(size_t)(mbase + r) * 512 + nl] = acc[i][j][r] + bias[j];
            } else {
                const int h = nl >> 6, hd = nl & 63;
                if (seg < 2) {
                    const float qs = (seg == 0) ? 0.125f : 1.f;  // pre-scale Q by 1/sqrt(64)
#pragma unroll
                    for (int r = 0; r < 4; r++) {
                        int m = mbase + r;
                        int s = m >> 10, tok = m & 1023;
                        O[(size_t)((s * 8 + h) * 1024 + tok) * 64 + hd] =
                            f2b((acc[i][j][r] + bias[j]) * qs);
                    }
                } else {
                    // V transposed: ((s*8+h)*64 + hd)*1024 + tok
                    int s = mbase >> 10, tok0 = mbase & 1023;
                    union { u16 us[4]; uint2 v; } pk;
#pragma unroll
                    for (int r = 0; r < 4; r++) pk.us[r] = f2b(acc[i][j][r] + bias[j]);
                    *(uint2*)&O[(size_t)((s * 8 + h) * 64 + hd) * 1024 + tok0] = pk.v;
                }
            }
        }
    }
}

// ---------------------------------------------------------------------------
// Attention v4: 1 wave per block, 32 q-rows per wave, all 1024 keys streamed.
// Halved per-wave register state vs round 4 -> 3-4 waves/SIMD occupancy with
// NO launch_bounds min-wave forcing (round 5's spill lesson: WRITE_SIZE is
// the scratch-spill tell). den = P @ ones via MFMA (row-indexed C-layout,
// no transpose/shfl). XCD decode: head = bid&127 -> same-head blocks on the
// same XCD -> K/V served from that XCD's L2 (16 heads x 256KB = 4MB = L2).
// ---------------------------------------------------------------------------
__global__ __launch_bounds__(64) void attn_kernel(const u16* __restrict__ Q,
                                                  const u16* __restrict__ Kp,
                                                  const u16* __restrict__ Vt,
                                                  u16* __restrict__ Ctx) {
    constexpr int SP = 72;  // P row stride: 16B-aligned frag reads, non-pow2 banks
    __shared__ __align__(16) u16 pl[32 * SP];  // 4.6 KB: 32 q-rows x 64 keys (+pad)

    const int bid = blockIdx.x;
    const int head = bid & 127;  // bid == head (mod 8) -> same XCD for a head's 32 blocks
    const int qt = bid >> 7;     // 0..31, 32 q-rows each
    const int s = head >> 3, h = head & 7;
    const u16* Qh = Q + (size_t)head * 65536;
    const u16* Kh = Kp + (size_t)head * 65536;
    const u16* Vh = Vt + (size_t)head * 65536;

    const int lane = threadIdx.x;
    const int quad = lane >> 4, col = lane & 15;
    const int q0 = qt * 32;

    // ones B-fragment for den = P @ ones
    union { u16 us[8]; bf16x8 v; } one;
#pragma unroll
    for (int i = 0; i < 8; i++) one.us[i] = 0x3F80;
    const bf16x8 onesf = one.v;

    // Q fragments (B-operand: lane holds Q[q=col][hd=quad*8+j]), loaded once
    bf16x8 qf[2][2];
#pragma unroll
    for (int nt = 0; nt < 2; nt++)
#pragma unroll
        for (int kk = 0; kk < 2; kk++)
            qf[nt][kk] = *(const bf16x8*)&Qh[(size_t)(q0 + nt * 16 + col) * 64 + kk * 32 + quad * 8];

    f32x4 cacc[2][4];  // [q-tile][hd-tile]
#pragma unroll
    for (int i = 0; i < 2; i++)
#pragma unroll
        for (int j = 0; j < 4; j++) cacc[i][j] = (f32x4){0.f, 0.f, 0.f, 0.f};
    f32x4 dacc[2];
#pragma unroll
    for (int i = 0; i < 2; i++) dacc[i] = (f32x4){0.f, 0.f, 0.f, 0.f};

    for (int kt = 0; kt < 16; kt++) {
        const int k0 = kt * 64;

        // ---- S^T = K * Q^T : M=64 keys (mt), N=32 q (nt), K=64 (kk) ----
        f32x4 sacc[4][2];
#pragma unroll
        for (int i = 0; i < 4; i++)
#pragma unroll
            for (int j = 0; j < 2; j++) sacc[i][j] = (f32x4){0.f, 0.f, 0.f, 0.f};
#pragma unroll
        for (int kk = 0; kk < 2; kk++) {
            bf16x8 kf[4];
#pragma unroll
            for (int mt = 0; mt < 4; mt++)
                kf[mt] = *(const bf16x8*)&Kh[(size_t)(k0 + mt * 16 + col) * 64 + kk * 32 + quad * 8];
#pragma unroll
            for (int mt = 0; mt < 4; mt++)
#pragma unroll
                for (int nt = 0; nt < 2; nt++)
                    sacc[mt][nt] =
                        __builtin_amdgcn_mfma_f32_16x16x32_bf16(kf[mt], qf[nt][kk], sacc[mt][nt], 0, 0, 0);
        }

        // relu + cheap bf16 pack (round-half-up + v_perm) -> LDS as P[q][key]
#pragma unroll
        for (int nt = 0; nt < 2; nt++) {
#pragma unroll
            for (int mt = 0; mt < 4; mt++) {
                unsigned u0 = __float_as_uint(fmaxf(sacc[mt][nt][0], 0.f)) + 0x8000u;
                unsigned u1 = __float_as_uint(fmaxf(sacc[mt][nt][1], 0.f)) + 0x8000u;
                unsigned u2 = __float_as_uint(fmaxf(sacc[mt][nt][2], 0.f)) + 0x8000u;
                unsigned u3 = __float_as_uint(fmaxf(sacc[mt][nt][3], 0.f)) + 0x8000u;
                uint2 pk;
                pk.x = __builtin_amdgcn_perm(u1, u0, 0x07060302);  // [u1.hi : u0.hi]
                pk.y = __builtin_amdgcn_perm(u3, u2, 0x07060302);
                // S^T C-layout: row(key)=mt*16+quad*4+r, col(q)=nt*16+col
                *(uint2*)&pl[(nt * 16 + col) * SP + mt * 16 + quad * 4] = pk;
            }
        }

        // ---- ctx += P @ V, den += P @ ones : M=32 q (pt), N=64 hd (nt) ----
#pragma unroll
        for (int kk = 0; kk < 2; kk++) {
            bf16x8 pf[2], vf[4];
#pragma unroll
            for (int pt = 0; pt < 2; pt++)
                pf[pt] = *(const bf16x8*)&pl[(pt * 16 + col) * SP + kk * 32 + quad * 8];
#pragma unroll
            for (int nt = 0; nt < 4; nt++)
                vf[nt] = *(const bf16x8*)&Vh[(size_t)(nt * 16 + col) * 1024 + k0 + kk * 32 + quad * 8];
#pragma unroll
            for (int pt = 0; pt < 2; pt++)
                dacc[pt] = __builtin_amdgcn_mfma_f32_16x16x32_bf16(pf[pt], onesf, dacc[pt], 0, 0, 0);
#pragma unroll
            for (int pt = 0; pt < 2; pt++)
#pragma unroll
                for (int nt = 0; nt < 4; nt++)
                    cacc[pt][nt] =
                        __builtin_amdgcn_mfma_f32_16x16x32_bf16(pf[pt], vf[nt], cacc[pt][nt], 0, 0, 0);
        }
    }

    // normalize + write ctx in (s, tok, h*64+hd) layout for the output GEMM
#pragma unroll
    for (int pt = 0; pt < 2; pt++) {
        float inv[4];
#pragma unroll
        for (int r = 0; r < 4; r++) inv[r] = 1.f / (dacc[pt][r] + 1e-6f);
#pragma unroll
        for (int nt = 0; nt < 4; nt++) {
#pragma unroll
            for (int r = 0; r < 4; r++) {
                const int row = pt * 16 + quad * 4 + r;
                const size_t grow = (size_t)(s * 1024 + q0 + row);
                Ctx[grow * 512 + h * 64 + nt * 16 + col] = f2b(cacc[pt][nt][r] * inv[r]);
            }
        }
    }
}

extern "C" void kernel_launch(void* const* d_in, const int* in_sizes, int n_in, void* d_out,
                              int out_size, void* d_ws, size_t ws_size, hipStream_t stream) {
    const float* x = (const float*)d_in[0];
    const float* wq = (const float*)d_in[1];
    const float* bq = (const float*)d_in[2];
    const float* wk = (const float*)d_in[3];
    const float* bk = (const float*)d_in[4];
    const float* wv = (const float*)d_in[5];
    const float* bv = (const float*)d_in[6];
    const float* wo = (const float*)d_in[7];
    const float* bo = (const float*)d_in[8];

    const size_t E = 16384ull * 512ull;
    u16* xb = (u16*)d_ws;  // bf16 x; aliased as ctx after gemm0 consumes it
    u16* cw = xb;
    u16* wb = xb + E;      // bf16 wq|wk|wv|wo
    u16* qw = wb + 4 * 262144;
    u16* kw = qw + E;
    u16* vw = kw + E;

    conv_kernel<<<dim3(4096 + 512), 256, 0, stream>>>(x, wq, wk, wv, wo, xb, wb);
    gemm_kernel<0><<<dim3(128, 12), 256, 0, stream>>>(xb, wb, bq, bk, bv, qw, kw, vw);
    attn_kernel<<<dim3(4096), 64, 0, stream>>>(qw, kw, vw, cw);
    gemm_kernel<1><<<dim3(128, 4), 256, 0, stream>>>(cw, wb + 3 * 262144, bo, nullptr, nullptr,
                                                     d_out, nullptr, nullptr);
}

// Round 7
// 206.344 us; speedup vs baseline: 1.7008x; 1.3992x over previous
//
#include <hip/hip_runtime.h>

typedef unsigned short u16;
typedef __attribute__((ext_vector_type(8))) short bf16x8;
typedef __attribute__((ext_vector_type(4))) float f32x4;

__device__ inline u16 f2b(float f) {
    unsigned u;
    __builtin_memcpy(&u, &f, 4);
    unsigned r = u + 0x7FFF + ((u >> 16) & 1);  // RNE
    return (u16)(r >> 16);
}

__device__ inline bf16x8 pack8(const float* p) {
    union { u16 us[8]; bf16x8 v; } r;
#pragma unroll
    for (int i = 0; i < 8; i++) r.us[i] = f2b(p[i]);
    return r.v;
}

// async global->LDS, 16B per lane. LDS dest is wave-uniform base + lane*16;
// the GLOBAL source per lane is arbitrary (this is what makes the XOR-swizzle
// staging below possible).
__device__ inline void gload16(const void* g, void* l) {
    __builtin_amdgcn_global_load_lds((__attribute__((address_space(1))) void*)g,
                                     (__attribute__((address_space(3))) void*)l, 16, 0, 0);
}

// ---------------------------------------------------------------------------
// One-shot fp32 -> bf16: x (4096 blocks) then wq,wk,wv,wo (128 each) into wb.
// ---------------------------------------------------------------------------
__global__ __launch_bounds__(256) void conv_kernel(const float* __restrict__ x,
                                                   const float* __restrict__ wq,
                                                   const float* __restrict__ wk,
                                                   const float* __restrict__ wv,
                                                   const float* __restrict__ wo,
                                                   u16* __restrict__ xb, u16* __restrict__ wb) {
    const int bid = blockIdx.x;
    const float* src;
    u16* dst;
    size_t base;
    if (bid < 4096) {
        src = x; dst = xb; base = (size_t)bid * 2048;
    } else {
        const int wsel = (bid - 4096) >> 7;
        src = (wsel == 0) ? wq : (wsel == 1) ? wk : (wsel == 2) ? wv : wo;
        dst = wb + (size_t)wsel * 262144;
        base = (size_t)((bid - 4096) & 127) * 2048;
    }
    const size_t idx = base + (size_t)threadIdx.x * 8;
    float a[8];
    *(float4*)&a[0] = *(const float4*)&src[idx];
    *(float4*)&a[4] = *(const float4*)&src[idx + 4];
    *(bf16x8*)&dst[idx] = pack8(a);
}

// ---------------------------------------------------------------------------
// bf16 GEMM (m97-style): C[m][n] = sum_k A[m][k]*W[n][k] + bias[n].
// global_load_lds 16B staging, 128x128 tile, BK=32, 4 waves, 4x4 16x16x32 frags.
// MODE 0: N=1536 (q|k|v rows of wb); scatter Q*0.125,K -> (s,h,tok,hd),
//         V -> transposed (s,h,hd,tok). MODE 1: fp32 row-major out (d_out).
// ---------------------------------------------------------------------------
template <int MODE>
__global__ __launch_bounds__(256) void gemm_kernel(const u16* __restrict__ A,
                                                   const u16* __restrict__ W,
                                                   const float* __restrict__ B0,
                                                   const float* __restrict__ B1,
                                                   const float* __restrict__ B2,
                                                   void* __restrict__ O0v, u16* __restrict__ O1,
                                                   u16* __restrict__ O2) {
    const int m0 = blockIdx.x * 128;
    const int n0 = blockIdx.y * 128;
    const int seg = (MODE == 0) ? (n0 >> 9) : 0;
    const int nl0 = (MODE == 0) ? (n0 & 511) : n0;
    const float* Bb = (seg == 0) ? B0 : (seg == 1) ? B1 : B2;
    u16* O = (seg == 0) ? (u16*)O0v : (seg == 1) ? O1 : O2;

    __shared__ __align__(16) u16 Al[128 * 32];
    __shared__ __align__(16) u16 Bl[128 * 32];

    const int tid = threadIdx.x;
    const int lane = tid & 63, wave = tid >> 6;
    const int quad = lane >> 4, col = lane & 15;
    const int wm = wave >> 1, wn = wave & 1;

    f32x4 acc[4][4];
#pragma unroll
    for (int i = 0; i < 4; i++)
#pragma unroll
        for (int j = 0; j < 4; j++) acc[i][j] = (f32x4){0.f, 0.f, 0.f, 0.f};

    for (int k0 = 0; k0 < 512; k0 += 32) {
#pragma unroll
        for (int sh = 0; sh < 4; sh++) {
            const int c = tid + sh * 256;  // 0..511 -> A tile, 512..1023 -> W tile
            const int cl = c & 511;
            const int row = cl >> 2, cc = (cl & 3) * 8;
            if (c < 512)
                gload16(&A[(size_t)(m0 + row) * 512 + k0 + cc], &Al[cl * 8]);
            else
                gload16(&W[(size_t)(n0 + row) * 512 + k0 + cc], &Bl[cl * 8]);
        }
        __syncthreads();
        bf16x8 af[4], bfr[4];
#pragma unroll
        for (int t = 0; t < 4; t++) {
            af[t] = *(const bf16x8*)&Al[(wm * 64 + t * 16 + col) * 32 + quad * 8];
            bfr[t] = *(const bf16x8*)&Bl[(wn * 64 + t * 16 + col) * 32 + quad * 8];
        }
#pragma unroll
        for (int i = 0; i < 4; i++)
#pragma unroll
            for (int j = 0; j < 4; j++)
                acc[i][j] = __builtin_amdgcn_mfma_f32_16x16x32_bf16(af[i], bfr[j], acc[i][j], 0, 0, 0);
        __syncthreads();
    }

    float bias[4];
#pragma unroll
    for (int j = 0; j < 4; j++) bias[j] = Bb[nl0 + wn * 64 + j * 16 + col];

#pragma unroll
    for (int i = 0; i < 4; i++) {
        const int mbase = m0 + wm * 64 + i * 16 + quad * 4;
#pragma unroll
        for (int j = 0; j < 4; j++) {
            const int nl = nl0 + wn * 64 + j * 16 + col;
            if (MODE == 1) {
                float* Of = (float*)O0v;  // fp32 final output
#pragma unroll
                for (int r = 0; r < 4; r++)
                    Of[(size_t)(mbase + r) * 512 + nl] = acc[i][j][r] + bias[j];
            } else {
                const int h = nl >> 6, hd = nl & 63;
                if (seg < 2) {
                    const float qs = (seg == 0) ? 0.125f : 1.f;  // pre-scale Q by 1/sqrt(64)
#pragma unroll
                    for (int r = 0; r < 4; r++) {
                        int m = mbase + r;
                        int s = m >> 10, tok = m & 1023;
                        O[(size_t)((s * 8 + h) * 1024 + tok) * 64 + hd] =
                            f2b((acc[i][j][r] + bias[j]) * qs);
                    }
                } else {
                    // V transposed: ((s*8+h)*64 + hd)*1024 + tok
                    int s = mbase >> 10, tok0 = mbase & 1023;
                    union { u16 us[4]; uint2 v; } pk;
#pragma unroll
                    for (int r = 0; r < 4; r++) pk.us[r] = f2b(acc[i][j][r] + bias[j]);
                    *(uint2*)&O[(size_t)((s * 8 + h) * 64 + hd) * 1024 + tok0] = pk.v;
                }
            }
        }
    }
}

// ---------------------------------------------------------------------------
// Attention v5 (flash-style shared staging): 4 waves / 256 thr per block,
// 128 q-rows per block (32 per wave). Per kt, the BLOCK stages the 64x64 K
// and V tiles into LDS once via global_load_lds (round-4/6 lesson: per-wave
// private K/V streaming is the bottleneck). K/V use an XOR-swizzled layout
// implemented on the DMA *source* side (LDS slot of chunk c in row r holds
// logical chunk c^(r&7)) so b128 frag reads hit all 8 bank-quads.
// den = P @ ones via MFMA. XCD decode: head = bid&127.
// LDS 34.8 KB -> 4 blocks/CU; no min-wave forcing (round-5 spill lesson).
// ---------------------------------------------------------------------------
__global__ __launch_bounds__(256) void attn_kernel(const u16* __restrict__ Q,
                                                   const u16* __restrict__ Kp,
                                                   const u16* __restrict__ Vt,
                                                   u16* __restrict__ Ctx) {
    constexpr int SP = 72;
    __shared__ __align__(16) u16 Kl[4096];      // 64 keys x 64 hd, XOR-swizzled chunks
    __shared__ __align__(16) u16 Vl[4096];      // 64 hd x 64 tok, XOR-swizzled chunks
    __shared__ __align__(16) u16 pl[4][32 * SP];

    const int bid = blockIdx.x;
    const int head = bid & 127;  // same-head blocks == mod 8 -> same XCD L2
    const int qt = bid >> 7;     // 0..7, 128 q-rows each
    const int s = head >> 3, h = head & 7;
    const u16* Qh = Q + (size_t)head * 65536;
    const u16* Kh = Kp + (size_t)head * 65536;
    const u16* Vh = Vt + (size_t)head * 65536;

    const int tid = threadIdx.x;
    const int lane = tid & 63, wave = tid >> 6;
    const int quad = lane >> 4, col = lane & 15;
    const int q0 = qt * 128 + wave * 32;

    // staging decode (hoisted): position p -> row, swizzled source chunk
    int srow[2], sxc[2];
#pragma unroll
    for (int i = 0; i < 2; i++) {
        const int p = tid + i * 256;
        srow[i] = p >> 3;
        sxc[i] = (p & 7) ^ (srow[i] & 7);
    }

    // ones B-fragment for den = P @ ones
    union { u16 us[8]; bf16x8 v; } one;
#pragma unroll
    for (int i = 0; i < 8; i++) one.us[i] = 0x3F80;
    const bf16x8 onesf = one.v;

    // Q fragments (B-operand: lane holds Q[q=col][hd=quad*8+j]), loaded once
    bf16x8 qf[2][2];
#pragma unroll
    for (int nt = 0; nt < 2; nt++)
#pragma unroll
        for (int kk = 0; kk < 2; kk++)
            qf[nt][kk] = *(const bf16x8*)&Qh[(size_t)(q0 + nt * 16 + col) * 64 + kk * 32 + quad * 8];

    f32x4 cacc[2][4];  // [q-tile][hd-tile]
#pragma unroll
    for (int i = 0; i < 2; i++)
#pragma unroll
        for (int j = 0; j < 4; j++) cacc[i][j] = (f32x4){0.f, 0.f, 0.f, 0.f};
    f32x4 dacc[2];
#pragma unroll
    for (int i = 0; i < 2; i++) dacc[i] = (f32x4){0.f, 0.f, 0.f, 0.f};

    const int cxor = col & 7;  // frag-read swizzle term (row & 7 == col & 7)

    for (int kt = 0; kt < 16; kt++) {
        const int k0 = kt * 64;

        // ---- block-shared staging: K tile + V tile -> LDS (async DMA) ----
#pragma unroll
        for (int i = 0; i < 2; i++) {
            const int p = tid + i * 256;
            gload16(&Kh[(size_t)(k0 + srow[i]) * 64 + sxc[i] * 8], &Kl[p * 8]);
        }
#pragma unroll
        for (int i = 0; i < 2; i++) {
            const int p = tid + i * 256;
            gload16(&Vh[(size_t)srow[i] * 1024 + k0 + sxc[i] * 8], &Vl[p * 8]);
        }
        __syncthreads();  // drains DMA (vmcnt) + guards Kl/Vl reuse

        // ---- S^T = K * Q^T : M=64 keys (mt), N=32 q (nt) ----
        f32x4 sacc[4][2];
#pragma unroll
        for (int i = 0; i < 4; i++)
#pragma unroll
            for (int j = 0; j < 2; j++) sacc[i][j] = (f32x4){0.f, 0.f, 0.f, 0.f};
#pragma unroll
        for (int kk = 0; kk < 2; kk++) {
            bf16x8 kf[4];
#pragma unroll
            for (int mt = 0; mt < 4; mt++)
                kf[mt] = *(const bf16x8*)&Kl[((mt * 16 + col) * 8 + ((kk * 4 + quad) ^ cxor)) * 8];
#pragma unroll
            for (int mt = 0; mt < 4; mt++)
#pragma unroll
                for (int nt = 0; nt < 2; nt++)
                    sacc[mt][nt] =
                        __builtin_amdgcn_mfma_f32_16x16x32_bf16(kf[mt], qf[nt][kk], sacc[mt][nt], 0, 0, 0);
        }

        // relu + cheap bf16 pack (round-half-up + v_perm) -> pl as P[q][key]
#pragma unroll
        for (int nt = 0; nt < 2; nt++) {
#pragma unroll
            for (int mt = 0; mt < 4; mt++) {
                unsigned u0 = __float_as_uint(fmaxf(sacc[mt][nt][0], 0.f)) + 0x8000u;
                unsigned u1 = __float_as_uint(fmaxf(sacc[mt][nt][1], 0.f)) + 0x8000u;
                unsigned u2 = __float_as_uint(fmaxf(sacc[mt][nt][2], 0.f)) + 0x8000u;
                unsigned u3 = __float_as_uint(fmaxf(sacc[mt][nt][3], 0.f)) + 0x8000u;
                uint2 pk;
                pk.x = __builtin_amdgcn_perm(u1, u0, 0x07060302);  // [u1.hi : u0.hi]
                pk.y = __builtin_amdgcn_perm(u3, u2, 0x07060302);
                // S^T C-layout: row(key)=mt*16+quad*4+r, col(q)=nt*16+col
                *(uint2*)&pl[wave][(nt * 16 + col) * SP + mt * 16 + quad * 4] = pk;
            }
        }

        // ---- ctx += P @ V, den += P @ ones : M=32 q (pt), N=64 hd (nt) ----
#pragma unroll
        for (int kk = 0; kk < 2; kk++) {
            bf16x8 pf[2], vf[4];
#pragma unroll
            for (int pt = 0; pt < 2; pt++)
                pf[pt] = *(const bf16x8*)&pl[wave][(pt * 16 + col) * SP + kk * 32 + quad * 8];
#pragma unroll
            for (int nt = 0; nt < 4; nt++)
                vf[nt] = *(const bf16x8*)&Vl[((nt * 16 + col) * 8 + ((kk * 4 + quad) ^ cxor)) * 8];
#pragma unroll
            for (int pt = 0; pt < 2; pt++)
                dacc[pt] = __builtin_amdgcn_mfma_f32_16x16x32_bf16(pf[pt], onesf, dacc[pt], 0, 0, 0);
#pragma unroll
            for (int pt = 0; pt < 2; pt++)
#pragma unroll
                for (int nt = 0; nt < 4; nt++)
                    cacc[pt][nt] =
                        __builtin_amdgcn_mfma_f32_16x16x32_bf16(pf[pt], vf[nt], cacc[pt][nt], 0, 0, 0);
        }
        __syncthreads();  // Kl/Vl consumed; safe to restage next kt
    }

    // normalize + write ctx in (s, tok, h*64+hd) layout for the output GEMM
#pragma unroll
    for (int pt = 0; pt < 2; pt++) {
        float inv[4];
#pragma unroll
        for (int r = 0; r < 4; r++) inv[r] = 1.f / (dacc[pt][r] + 1e-6f);
#pragma unroll
        for (int nt = 0; nt < 4; nt++) {
#pragma unroll
            for (int r = 0; r < 4; r++) {
                const int row = pt * 16 + quad * 4 + r;
                const size_t grow = (size_t)(s * 1024 + q0 + row);
                Ctx[grow * 512 + h * 64 + nt * 16 + col] = f2b(cacc[pt][nt][r] * inv[r]);
            }
        }
    }
}

extern "C" void kernel_launch(void* const* d_in, const int* in_sizes, int n_in, void* d_out,
                              int out_size, void* d_ws, size_t ws_size, hipStream_t stream) {
    const float* x = (const float*)d_in[0];
    const float* wq = (const float*)d_in[1];
    const float* bq = (const float*)d_in[2];
    const float* wk = (const float*)d_in[3];
    const float* bk = (const float*)d_in[4];
    const float* wv = (const float*)d_in[5];
    const float* bv = (const float*)d_in[6];
    const float* wo = (const float*)d_in[7];
    const float* bo = (const float*)d_in[8];

    const size_t E = 16384ull * 512ull;
    u16* xb = (u16*)d_ws;  // bf16 x; aliased as ctx after gemm0 consumes it
    u16* cw = xb;
    u16* wb = xb + E;      // bf16 wq|wk|wv|wo
    u16* qw = wb + 4 * 262144;
    u16* kw = qw + E;
    u16* vw = kw + E;

    conv_kernel<<<dim3(4096 + 512), 256, 0, stream>>>(x, wq, wk, wv, wo, xb, wb);
    gemm_kernel<0><<<dim3(128, 12), 256, 0, stream>>>(xb, wb, bq, bk, bv, qw, kw, vw);
    attn_kernel<<<dim3(1024), 256, 0, stream>>>(qw, kw, vw, cw);
    gemm_kernel<1><<<dim3(128, 4), 256, 0, stream>>>(cw, wb + 3 * 262144, bo, nullptr, nullptr,
                                                     d_out, nullptr, nullptr);
}